// Round 8
// baseline (1706.044 us; speedup 1.0000x reference)
//
#include <hip/hip_runtime.h>
#include <hip/hip_bf16.h>
#include <math.h>

#define H 768
#define NB 2048
#define DD 16
#define VELOFF 36864
// packed gate matrix: 3072 cols = 48 tiles x (16 r | 16 z | 16 in | 16 hn), K = 800 = 768 h + 16 vel + 16 pad
// B field structure: r,z cols use K 0..784; in uses only 768..784 (vel); hn uses only 0..768 (h).

typedef __attribute__((ext_vector_type(8))) short bf16x8;
typedef __attribute__((ext_vector_type(4))) float f32x4;

__device__ __forceinline__ void gload_lds16(const void* g, void* lds) {
  __builtin_amdgcn_global_load_lds((const __attribute__((address_space(1))) void*)g,
                                   (__attribute__((address_space(3))) void*)lds, 16, 0, 0);
}
__device__ __forceinline__ float b2f(short s) {
  union { unsigned int u; float f; } c;
  c.u = ((unsigned int)(unsigned short)s) << 16;
  return c.f;
}
__device__ __forceinline__ short f2bs(float f) {
  __hip_bfloat16 h = __float2bfloat16(f);
  return *(short*)&h;
}

// ---------- prep 1: packed bias, B2g (interleaved e2 Wih h-part), velall ----------
__global__ void k_prep(const float* __restrict__ e1W, const float* __restrict__ e2W,
                       const float* __restrict__ dW, const float* __restrict__ embB,
                       const float* b1i, const float* b1h, const float* b2i, const float* b2h,
                       const float* b3i, const float* b3h, const float* __restrict__ obs,
                       float* __restrict__ biasP, __hip_bfloat16* __restrict__ B2g,
                       __hip_bfloat16* __restrict__ velall) {
  const int stride = gridDim.x * 256;
  const int gt = blockIdx.x * 256 + threadIdx.x;
  // biasP [3][3072] with emb_b fold
  for (int idx = gt; idx < 3 * 3072; idx += stride) {
    int c = idx % 3072, s = idx / 3072;
    int f = (c >> 4) & 3, u = (c >> 6) * 16 + (c & 15);
    const float* W = s == 0 ? e1W : s == 1 ? e2W : dW;
    int ld = s == 1 ? 1024 : 256;
    const float* bi = s == 0 ? b1i : s == 1 ? b2i : b3i;
    const float* bh = s == 0 ? b1h : s == 1 ? b2h : b3h;
    float v;
    if (f == 3) {
      v = bh[1536 + u];
    } else {
      int g = (f < 2 ? f * 768 : 1536) + u;
      float acc = bi[g] + (f < 2 ? bh[g] : 0.f);
      for (int e = 0; e < 256; ++e) acc += W[(size_t)g * ld + e] * embB[e];
      v = acc;
    }
    biasP[idx] = v;
  }
  // B2g [3072][768] interleaved
  for (int idx = gt; idx < 3072 * 768; idx += stride) {
    int k = idx % 768, c = idx / 768;
    int f = (c >> 4) & 3, u = (c >> 6) * 16 + (c & 15);
    float v = (f < 3) ? e2W[(size_t)(f * 768 + u) * 1024 + 256 + k] : 0.f;
    B2g[idx] = __float2bfloat16(v);
  }
  // velall [7][2048][32] padded
  for (int idx = gt; idx < 7 * 2048 * 32; idx += stride) {
    int d = idx & 31, n = (idx >> 5) & 2047, s = idx >> 16;
    float v = 0.f;
    if (d < 16)
      v = obs[((size_t)(s + 1) * NB + n) * DD + d] - obs[((size_t)s * NB + n) * DD + d];
    velall[idx] = __float2bfloat16(v);
  }
}

// ---------- prep 2: pack Bp[3072][800] x3, with M1 (=4*Wih@embW) inlined for vel cols ----------
__global__ void k_packB3(const float* __restrict__ W1h, const float* __restrict__ W2h,
                         const float* __restrict__ W3h, const float* __restrict__ W1i,
                         const float* __restrict__ W2i, const float* __restrict__ W3i,
                         const float* __restrict__ embW,
                         __hip_bfloat16* __restrict__ B1, __hip_bfloat16* __restrict__ B2,
                         __hip_bfloat16* __restrict__ B3) {
  int idx = blockIdx.x * 256 + threadIdx.x;  // < 3072*800
  if (idx >= 3072 * 800) return;
  int s = blockIdx.y;
  const float* Whh = s == 0 ? W1h : s == 1 ? W2h : W3h;
  const float* Wih = s == 0 ? W1i : s == 1 ? W2i : W3i;
  int ldih = s == 1 ? 1024 : 256;
  __hip_bfloat16* Bp = s == 0 ? B1 : s == 1 ? B2 : B3;
  int k = idx % 800, c = idx / 800;
  int f = (c >> 4) & 3, u = (c >> 6) * 16 + (c & 15);
  float v = 0.f;
  if (k < 768) {
    if (f == 0) v = Whh[(size_t)u * 768 + k];
    else if (f == 1) v = Whh[(size_t)(768 + u) * 768 + k];
    else if (f == 3) v = Whh[(size_t)(1536 + u) * 768 + k];
  } else if (k < 784 && f < 3) {
    int g = (f < 2 ? f * 768 : 1536) + u;
    float acc = 0.f;
    int d = k - 768;
    for (int e = 0; e < 256; ++e) acc += Wih[(size_t)g * ldih + e] * embW[e * 16 + d];
    v = 4.0f * acc;
  }
  Bp[idx] = __float2bfloat16(v);
}

// ---------- plain GEMM for g2add: C[2048][3072] = A(2048x768) @ B(3072x768)^T ----------
__global__ __launch_bounds__(256) void k_plain(
    const __hip_bfloat16* __restrict__ A, const __hip_bfloat16* __restrict__ B,
    __hip_bfloat16* __restrict__ C, int ldc) {
  __shared__ __align__(16) __hip_bfloat16 Asm[128 * 32];
  __shared__ __align__(16) __hip_bfloat16 Bsm[128 * 32];
  const int tid = threadIdx.x;
  const int w = tid >> 6, l = tid & 63;
  const int bm = blockIdx.y, bn = blockIdx.x;
  const int wm = w >> 1, wn = w & 1;
  const int lr = l & 15, lk = l >> 4;
  const int ks = (((tid & 3) ^ ((tid >> 3) & 3)) << 3);
  const int lks = ((lk ^ ((lr >> 1) & 3)) << 3);
  f32x4 acc[4][4];
#pragma unroll
  for (int m = 0; m < 4; ++m)
#pragma unroll
    for (int n = 0; n < 4; ++n) acc[m][n] = (f32x4){0.f, 0.f, 0.f, 0.f};
  const int rowA = bm * 128, rowB = bn * 128;
  const int rA = tid >> 2;
  for (int kb = 0; kb < H; kb += 32) {
#pragma unroll
    for (int i = 0; i < 2; ++i) {
      int r = i * 64 + rA;
      gload_lds16(A + (size_t)(rowA + r) * H + kb + ks, (char*)Asm + i * 4096 + w * 1024);
      gload_lds16(B + (size_t)(rowB + r) * H + kb + ks, (char*)Bsm + i * 4096 + w * 1024);
    }
    __syncthreads();
    bf16x8 af[4], bfr[4];
#pragma unroll
    for (int m = 0; m < 4; ++m)
      af[m] = *(const bf16x8*)(Asm + (wm * 64 + m * 16 + lr) * 32 + lks);
#pragma unroll
    for (int n = 0; n < 4; ++n)
      bfr[n] = *(const bf16x8*)(Bsm + (wn * 64 + n * 16 + lr) * 32 + lks);
#pragma unroll
    for (int m = 0; m < 4; ++m)
#pragma unroll
      for (int n = 0; n < 4; ++n)
        acc[m][n] = __builtin_amdgcn_mfma_f32_16x16x32_bf16(af[m], bfr[n], acc[m][n], 0, 0, 0);
    __syncthreads();
  }
#pragma unroll
  for (int m = 0; m < 4; ++m)
#pragma unroll
    for (int n = 0; n < 4; ++n) {
      int col = bn * 128 + wn * 64 + n * 16 + lr;
#pragma unroll
      for (int r4 = 0; r4 < 4; ++r4) {
        int row = rowA + wm * 64 + m * 16 + lk * 4 + r4;
        C[(size_t)row * ldc + col] = __float2bfloat16(acc[m][n][r4]);
      }
    }
}

// ---------- fused step: 128x64 tile, 3-deep ring + vel LDS region, optional fused head ----------
// grid (48, 16), 256 threads, 44KB LDS -> 3 blocks/CU.
// MODE 0: vel region staged from global vel[2048][32]. MODE 1: fused decoder head computes vel.
template <int MODE>
__global__ __launch_bounds__(256, 3) void k_step(
    const __hip_bfloat16* __restrict__ hin,  // null => h=0 step (MODE 0 only)
    const __hip_bfloat16* __restrict__ vel,  // MODE 0: [2048][32]
    const __hip_bfloat16* __restrict__ Bp,   // 3072 x 800
    const float* __restrict__ bias,          // 3072 packed (set base)
    const __hip_bfloat16* __restrict__ g2a,  // e2 h_inv addend or null
    __hip_bfloat16* __restrict__ hout,
    const float* __restrict__ h2n_W, const float* __restrict__ h2n_b,
    const float* __restrict__ mix_W, const float* __restrict__ mix_b,
    const float* __restrict__ o2,            // MODE 1: obs2 rows for head
    float* __restrict__ rel_out, float* __restrict__ pos_out) {
  __shared__ __align__(16) char lds[45056];  // 3x12288 ring + 8KB vel region @36864
  const int tid = threadIdx.x;
  const int w = tid >> 6, l = tid & 63;
  const int nt = blockIdx.x, bm = blockIdx.y;
  const int rowA = bm * 128, colB = nt * 64;
  const int lr = l & 15, lk = l >> 4;
  const int rS = tid >> 2;
  const int ce = (((tid & 3) ^ ((tid >> 3) & 3)) << 3);   // swizzled source octet
  const int lks = ((lk ^ ((lr >> 1) & 3)) << 3);          // swizzled read octet
  const int wbase = w * 1024;

  auto STAGE = [&](int buf, int kb) {
#pragma unroll
    for (int i_ = 0; i_ < 2; ++i_)
      gload_lds16(hin + (size_t)(rowA + i_ * 64 + rS) * H + kb + ce,
                  lds + buf * 12288 + i_ * 4096 + wbase);
    gload_lds16(Bp + (size_t)(colB + rS) * 800 + kb + ce, lds + buf * 12288 + 8192 + wbase);
  };

  if (MODE == 0) {
    // vel region from global (2 loads)
#pragma unroll
    for (int i_ = 0; i_ < 2; ++i_)
      gload_lds16(vel + (size_t)(rowA + i_ * 64 + rS) * 32 + ce,
                  lds + VELOFF + i_ * 4096 + wbase);
  }
  if (hin) { STAGE(0, 0); STAGE(1, 32); }
  else     gload_lds16(Bp + (size_t)(colB + rS) * 800 + 768 + ce, lds + 8192 + wbase);

  if (MODE == 1) {
    // ---- fused head for previous decoder step (redundant per block) ----
    const int hr = tid >> 1, p = tid & 1;
    const short* hrow = (const short*)hin + (size_t)(rowA + hr) * H + p * 384;
    float s0 = 0.f, s1 = 0.f, s2 = 0.f, s3 = 0.f, s4 = 0.f;
    for (int kk = 0; kk < 384; kk += 8) {
      bf16x8 h8 = *(const bf16x8*)(hrow + kk);
#pragma unroll
      for (int e = 0; e < 8; ++e) {
        float hv = b2f(h8[e]);
        int k2 = p * 384 + kk + e;
        s0 += hv * h2n_W[k2];
        s1 += hv * h2n_W[768 + k2];
        s2 += hv * h2n_W[1536 + k2];
        s3 += hv * h2n_W[2304 + k2];
        s4 += hv * h2n_W[3072 + k2];
      }
    }
    s0 += __shfl_xor(s0, 1); s1 += __shfl_xor(s1, 1); s2 += __shfl_xor(s2, 1);
    s3 += __shfl_xor(s3, 1); s4 += __shfl_xor(s4, 1);
    float n0 = s0 + h2n_b[0], n1 = s1 + h2n_b[1];
    float x2 = s2 + h2n_b[2], x3 = s3 + h2n_b[3], x4 = s4 + h2n_b[4];
    float n2 = 0.01f + 0.2f * (x2 > 0.f ? x2 + log1pf(expf(-x2)) : log1pf(expf(x2)));
    float n3 = 0.01f + 0.2f * (x3 > 0.f ? x3 + log1pf(expf(-x3)) : log1pf(expf(x3)));
    float n4 = 0.7f * tanhf(x4);
    union { bf16x8 v; short s[8]; } pk;
#pragma unroll
    for (int e = 0; e < 8; ++e) {
      int d = p * 8 + e;
      float a = mix_b[d] + n0 * mix_W[d * 5 + 0] + n1 * mix_W[d * 5 + 1] +
                n2 * mix_W[d * 5 + 2] + n3 * mix_W[d * 5 + 3] + n4 * mix_W[d * 5 + 4];
      float rl = fmaxf(a, 0.f);
      pk.s[e] = f2bs(rl);
      if (nt == 0)
        pos_out[(size_t)(rowA + hr) * DD + d] = o2[(size_t)(rowA + hr) * DD + d] + rl;
    }
    if (nt == 0 && p == 0) {
      float* rp = rel_out + (size_t)(rowA + hr) * 5;
      rp[0] = n0; rp[1] = n1; rp[2] = n2; rp[3] = n3; rp[4] = n4;
    }
    // swizzled write into vel region: dest octet j holds source octet j^((row>>1)&3)
    int swz = (hr >> 1) & 3;
    *(bf16x8*)(lds + VELOFF + hr * 64 + ((p ^ swz) << 4)) = pk.v;
    bf16x8 z8 = {};
    *(bf16x8*)(lds + VELOFF + hr * 64 + (((2 + p) ^ swz) << 4)) = z8;
    asm volatile("s_waitcnt lgkmcnt(0)" ::: "memory");
    __builtin_amdgcn_s_barrier();
  }

  f32x4 acc[2][4];
#pragma unroll
  for (int m = 0; m < 2; ++m)
#pragma unroll
    for (int n = 0; n < 4; ++n) acc[m][n] = (f32x4){0.f, 0.f, 0.f, 0.f};

  if (hin) {
#pragma unroll
    for (int ki = 0; ki < 25; ++ki) {
      if (ki <= 22)      asm volatile("s_waitcnt vmcnt(3)" ::: "memory");
      else if (ki == 23) asm volatile("s_waitcnt vmcnt(1)" ::: "memory");
      else               asm volatile("s_waitcnt vmcnt(0)" ::: "memory");
      __builtin_amdgcn_sched_barrier(0);
      __builtin_amdgcn_s_barrier();
      __builtin_amdgcn_sched_barrier(0);
      if (ki < 22) STAGE((ki + 2) % 3, (ki + 2) * 32);
      else if (ki == 22)  // chunk 24: B-only (A comes from vel region)
        gload_lds16(Bp + (size_t)(colB + rS) * 800 + 768 + ce, lds + 8192 + wbase);
      const bool last = (ki == 24);
      const __hip_bfloat16* Ab = last ? (const __hip_bfloat16*)(lds + VELOFF)
                                      : (const __hip_bfloat16*)(lds + (ki % 3) * 12288);
      const __hip_bfloat16* Bb = (const __hip_bfloat16*)(lds + (ki % 3) * 12288 + 8192);
      bf16x8 a0 = *(const bf16x8*)(Ab + (w * 32 + lr) * 32 + lks);
      bf16x8 a1 = *(const bf16x8*)(Ab + (w * 32 + 16 + lr) * 32 + lks);
      bf16x8 b0 = *(const bf16x8*)(Bb + lr * 32 + lks);
      bf16x8 b1 = *(const bf16x8*)(Bb + (16 + lr) * 32 + lks);
      bf16x8 b2 = *(const bf16x8*)(Bb + ((last ? 32 : 48) + lr) * 32 + lks);
      __builtin_amdgcn_s_setprio(1);
      acc[0][0] = __builtin_amdgcn_mfma_f32_16x16x32_bf16(a0, b0, acc[0][0], 0, 0, 0);
      acc[1][0] = __builtin_amdgcn_mfma_f32_16x16x32_bf16(a1, b0, acc[1][0], 0, 0, 0);
      acc[0][1] = __builtin_amdgcn_mfma_f32_16x16x32_bf16(a0, b1, acc[0][1], 0, 0, 0);
      acc[1][1] = __builtin_amdgcn_mfma_f32_16x16x32_bf16(a1, b1, acc[1][1], 0, 0, 0);
      if (last) {
        acc[0][2] = __builtin_amdgcn_mfma_f32_16x16x32_bf16(a0, b2, acc[0][2], 0, 0, 0);
        acc[1][2] = __builtin_amdgcn_mfma_f32_16x16x32_bf16(a1, b2, acc[1][2], 0, 0, 0);
      } else {
        acc[0][3] = __builtin_amdgcn_mfma_f32_16x16x32_bf16(a0, b2, acc[0][3], 0, 0, 0);
        acc[1][3] = __builtin_amdgcn_mfma_f32_16x16x32_bf16(a1, b2, acc[1][3], 0, 0, 0);
      }
      __builtin_amdgcn_s_setprio(0);
    }
  } else {
    // h == 0: single vel chunk
    asm volatile("s_waitcnt vmcnt(0)" ::: "memory");
    __builtin_amdgcn_sched_barrier(0);
    __builtin_amdgcn_s_barrier();
    __builtin_amdgcn_sched_barrier(0);
    const __hip_bfloat16* Ab = (const __hip_bfloat16*)(lds + VELOFF);
    const __hip_bfloat16* Bb = (const __hip_bfloat16*)(lds + 8192);
    bf16x8 a0 = *(const bf16x8*)(Ab + (w * 32 + lr) * 32 + lks);
    bf16x8 a1 = *(const bf16x8*)(Ab + (w * 32 + 16 + lr) * 32 + lks);
    bf16x8 b0 = *(const bf16x8*)(Bb + lr * 32 + lks);
    bf16x8 b1 = *(const bf16x8*)(Bb + (16 + lr) * 32 + lks);
    bf16x8 b2 = *(const bf16x8*)(Bb + (32 + lr) * 32 + lks);
    acc[0][0] = __builtin_amdgcn_mfma_f32_16x16x32_bf16(a0, b0, acc[0][0], 0, 0, 0);
    acc[1][0] = __builtin_amdgcn_mfma_f32_16x16x32_bf16(a1, b0, acc[1][0], 0, 0, 0);
    acc[0][1] = __builtin_amdgcn_mfma_f32_16x16x32_bf16(a0, b1, acc[0][1], 0, 0, 0);
    acc[1][1] = __builtin_amdgcn_mfma_f32_16x16x32_bf16(a1, b1, acc[1][1], 0, 0, 0);
    acc[0][2] = __builtin_amdgcn_mfma_f32_16x16x32_bf16(a0, b2, acc[0][2], 0, 0, 0);
    acc[1][2] = __builtin_amdgcn_mfma_f32_16x16x32_bf16(a1, b2, acc[1][2], 0, 0, 0);
  }

  __syncthreads();
  // biased pre-activations -> LDS tile [128][72] bf16
  short* T = (short*)lds;
#pragma unroll
  for (int n = 0; n < 4; ++n) {
    float bv = bias[colB + n * 16 + lr];
#pragma unroll
    for (int m = 0; m < 2; ++m) {
      int rbase = w * 32 + m * 16 + lk * 4;
#pragma unroll
      for (int r4 = 0; r4 < 4; ++r4)
        T[(rbase + r4) * 72 + n * 16 + lr] = f2bs(acc[m][n][r4] + bv);
    }
  }
  __syncthreads();

  // GRU: 128 rows x 16 units; 256 threads x 8 units
  const int row = tid >> 1;
  const int ub = (tid & 1) * 8;
  const size_t grow = (size_t)(rowA + row);
  const short* Tp = T + row * 72;
  bf16x8 Lr = *(const bf16x8*)(Tp + ub);
  bf16x8 Lz = *(const bf16x8*)(Tp + 16 + ub);
  bf16x8 Li = *(const bf16x8*)(Tp + 32 + ub);
  bf16x8 Lh = *(const bf16x8*)(Tp + 48 + ub);
  bf16x8 h8 = {};
  if (hin) h8 = *(const bf16x8*)(hin + grow * H + nt * 16 + ub);
  bf16x8 gr = {}, gz = {}, gi_ = {};
  if (g2a) {
    const __hip_bfloat16* gp = g2a + grow * 3072 + colB;
    gr  = *(const bf16x8*)(gp + ub);
    gz  = *(const bf16x8*)(gp + 16 + ub);
    gi_ = *(const bf16x8*)(gp + 32 + ub);
  }
  union { bf16x8 v; short s[8]; } ob;
#pragma unroll
  for (int e = 0; e < 8; ++e) {
    float xr = b2f(Lr[e]), xz = b2f(Lz[e]), xi = b2f(Li[e]), xh = b2f(Lh[e]);
    if (g2a) { xr += b2f(gr[e]); xz += b2f(gz[e]); xi += b2f(gi_[e]); }
    float r = 1.f / (1.f + expf(-xr));
    float z = 1.f / (1.f + expf(-xz));
    float nn = tanhf(xi + r * xh);
    float hv = hin ? ((1.f - z) * nn + z * b2f(h8[e])) : ((1.f - z) * nn);
    ob.s[e] = f2bs(hv);
  }
  *(bf16x8*)(hout + grow * H + nt * 16 + ub) = ob.v;
}

// ---------- final standalone head (k = 11) ----------
__global__ void k_headF(const __hip_bfloat16* __restrict__ h, const float* __restrict__ obs2,
                        const float* __restrict__ h2n_W, const float* __restrict__ h2n_b,
                        const float* __restrict__ mix_W, const float* __restrict__ mix_b,
                        float* __restrict__ rel_out, float* __restrict__ pos_out) {
  int wv = threadIdx.x >> 6, lane = threadIdx.x & 63;
  int row = blockIdx.x * 4 + wv;
  float s0 = 0.f, s1 = 0.f, s2 = 0.f, s3 = 0.f, s4 = 0.f;
  for (int k = lane; k < H; k += 64) {
    float hv = b2f(((const short*)h)[(size_t)row * H + k]);
    s0 += hv * h2n_W[k];
    s1 += hv * h2n_W[H + k];
    s2 += hv * h2n_W[2 * H + k];
    s3 += hv * h2n_W[3 * H + k];
    s4 += hv * h2n_W[4 * H + k];
  }
#pragma unroll
  for (int off = 32; off; off >>= 1) {
    s0 += __shfl_down(s0, off);
    s1 += __shfl_down(s1, off);
    s2 += __shfl_down(s2, off);
    s3 += __shfl_down(s3, off);
    s4 += __shfl_down(s4, off);
  }
  s0 = __shfl(s0, 0); s1 = __shfl(s1, 0); s2 = __shfl(s2, 0);
  s3 = __shfl(s3, 0); s4 = __shfl(s4, 0);
  float n0 = s0 + h2n_b[0], n1 = s1 + h2n_b[1];
  float x2 = s2 + h2n_b[2], x3 = s3 + h2n_b[3], x4 = s4 + h2n_b[4];
  float n2 = 0.01f + 0.2f * (x2 > 0.f ? x2 + log1pf(expf(-x2)) : log1pf(expf(x2)));
  float n3 = 0.01f + 0.2f * (x3 > 0.f ? x3 + log1pf(expf(-x3)) : log1pf(expf(x3)));
  float n4 = 0.7f * tanhf(x4);
  if (lane < DD) {
    float a = mix_b[lane] + n0 * mix_W[lane * 5 + 0] + n1 * mix_W[lane * 5 + 1] +
              n2 * mix_W[lane * 5 + 2] + n3 * mix_W[lane * 5 + 3] + n4 * mix_W[lane * 5 + 4];
    float rl = a > 0.f ? a : 0.f;
    pos_out[(size_t)row * DD + lane] = obs2[(size_t)row * DD + lane] + rl;
  }
  if (lane == 0) {
    rel_out[(size_t)row * 5 + 0] = n0;
    rel_out[(size_t)row * 5 + 1] = n1;
    rel_out[(size_t)row * 5 + 2] = n2;
    rel_out[(size_t)row * 5 + 3] = n3;
    rel_out[(size_t)row * 5 + 4] = n4;
  }
}

extern "C" void kernel_launch(void* const* d_in, const int* in_sizes, int n_in,
                              void* d_out, int out_size, void* d_ws, size_t ws_size,
                              hipStream_t stream) {
  (void)in_sizes; (void)n_in; (void)out_size; (void)ws_size;
  const float* observed = (const float*)d_in[0];
  const float* emb_W   = (const float*)d_in[1];
  const float* emb_b   = (const float*)d_in[2];
  const float* e1_Wih  = (const float*)d_in[3];
  const float* e1_Whh  = (const float*)d_in[4];
  const float* e1_bih  = (const float*)d_in[5];
  const float* e1_bhh  = (const float*)d_in[6];
  const float* e2_Wih  = (const float*)d_in[7];
  const float* e2_Whh  = (const float*)d_in[8];
  const float* e2_bih  = (const float*)d_in[9];
  const float* e2_bhh  = (const float*)d_in[10];
  const float* dec_Wih = (const float*)d_in[11];
  const float* dec_Whh = (const float*)d_in[12];
  const float* dec_bih = (const float*)d_in[13];
  const float* dec_bhh = (const float*)d_in[14];
  const float* h2n_W   = (const float*)d_in[15];
  const float* h2n_b   = (const float*)d_in[16];
  const float* mix_W   = (const float*)d_in[17];
  const float* mix_b   = (const float*)d_in[18];

  char* p = (char*)d_ws;
  auto alloc = [&](size_t bytes) { char* r = p; p += (bytes + 255) & ~(size_t)255; return r; };

  __hip_bfloat16* hp0    = (__hip_bfloat16*)alloc((size_t)NB * H * 2);
  __hip_bfloat16* hp1    = (__hip_bfloat16*)alloc((size_t)NB * H * 2);
  __hip_bfloat16* velall = (__hip_bfloat16*)alloc((size_t)7 * NB * 32 * 2);
  __hip_bfloat16* Bp1    = (__hip_bfloat16*)alloc((size_t)3072 * 800 * 2);
  __hip_bfloat16* Bp2    = (__hip_bfloat16*)alloc((size_t)3072 * 800 * 2);
  __hip_bfloat16* Bp3    = (__hip_bfloat16*)alloc((size_t)3072 * 800 * 2);
  __hip_bfloat16* B2g    = (__hip_bfloat16*)alloc((size_t)3072 * 768 * 2);
  __hip_bfloat16* g2add  = (__hip_bfloat16*)alloc((size_t)NB * 3072 * 2);
  float*          biasP  = (float*)alloc((size_t)3 * 3072 * 4);

  // ---- prep (2 launches) ----
  k_prep<<<1024, 256, 0, stream>>>(e1_Wih, e2_Wih, dec_Wih, emb_b,
                                   e1_bih, e1_bhh, e2_bih, e2_bhh, dec_bih, dec_bhh,
                                   observed, biasP, B2g, velall);
  k_packB3<<<dim3((3072 * 800 + 255) / 256, 3), 256, 0, stream>>>(
      e1_Whh, e2_Whh, dec_Whh, e1_Wih, e2_Wih, dec_Wih, emb_W, Bp1, Bp2, Bp3);

  dim3 gs(48, 16);
  float* rel  = (float*)d_out;                       // (12, 2048, 5)
  float* pred = (float*)d_out + (size_t)12 * NB * 5; // (12, 2048, 16)
  const __hip_bfloat16* src = nullptr;
  __hip_bfloat16* dst = hp0;
  auto flip = [&]() { src = dst; dst = (dst == hp0) ? hp1 : hp0; };

  // ---- encoder 1: velocity frames 6..0 (t=0: h=0) ----
  for (int t = 0; t < 7; ++t) {
    k_step<0><<<gs, 256, 0, stream>>>(t == 0 ? nullptr : src,
                                      velall + (size_t)(6 - t) * NB * 32, Bp1, biasP,
                                      nullptr, dst, h2n_W, h2n_b, mix_W, mix_b,
                                      nullptr, nullptr, nullptr);
    flip();
  }
  k_plain<<<dim3(24, 16), 256, 0, stream>>>(src, B2g, g2add, 3072);

  // ---- encoder 2: frames 0..6 (t=0: h=0) ----
  for (int t = 0; t < 7; ++t) {
    k_step<0><<<gs, 256, 0, stream>>>(t == 0 ? nullptr : src,
                                      velall + (size_t)t * NB * 32, Bp2, biasP + 3072,
                                      g2add, dst, h2n_W, h2n_b, mix_W, mix_b,
                                      nullptr, nullptr, nullptr);
    flip();
  }

  // ---- decoder step 0 (vel = frame 6) ----
  k_step<0><<<gs, 256, 0, stream>>>(src, velall + (size_t)6 * NB * 32, Bp3, biasP + 6144,
                                    nullptr, dst, h2n_W, h2n_b, mix_W, mix_b,
                                    nullptr, nullptr, nullptr);
  flip();
  // ---- decoder steps 1..11: fused head_{j} (j = step-1) at top ----
  for (int j = 0; j <= 10; ++j) {
    const float* o2 = (j == 0) ? observed + (size_t)7 * NB * DD
                               : pred + (size_t)(j - 1) * NB * DD;
    k_step<1><<<gs, 256, 0, stream>>>(src, nullptr, Bp3, biasP + 6144,
                                      nullptr, dst, h2n_W, h2n_b, mix_W, mix_b,
                                      o2, rel + (size_t)j * NB * 5, pred + (size_t)j * NB * DD);
    flip();
  }
  // ---- final head (k = 11) ----
  k_headF<<<NB / 4, 256, 0, stream>>>(src, pred + (size_t)10 * NB * DD,
                                      h2n_W, h2n_b, mix_W, mix_b,
                                      rel + (size_t)11 * NB * 5, pred + (size_t)11 * NB * DD);
}